// Round 8
// baseline (214.333 us; speedup 1.0000x reference)
//
#include <hip/hip_runtime.h>
#include <hip/hip_fp16.h>

#define B_   8
#define CIN  256
#define T_   4096
#define TP   4097    // padded T (row 0 = zeros, row t+1 = x[t])
#define CO   256
#define O4   1024
#define NN   32768   // B_*T_
#define NCH  128     // chunks along T
#define CL   32      // chunk length

// ws layout (float offsets)
#define OFF_XHI  0           // ushort [8][4097][256]
#define OFF_XLO  4195328
#define OFF_WHI  8390656     // ushort [1024][512]
#define OFF_WLO  8652800
#define OFF_F16  8914944     // ushort(f16) [8][4096][256]
#define OFF_IZ16 13109248
#define OFF_O16  17303552
#define OFF_A    21497856    // float [8][128][256]
#define OFF_B    21760000

typedef __attribute__((ext_vector_type(8))) short short8;
typedef __attribute__((ext_vector_type(4))) float floatx4;

__device__ __forceinline__ float fsig(float x)  { return 1.0f / (1.0f + __expf(-x)); }
__device__ __forceinline__ float ftanh(float x) { return 2.0f / (1.0f + __expf(-2.0f * x)) - 1.0f; }

__device__ __forceinline__ unsigned short bf16_rne(float v) {
    unsigned u = __float_as_uint(v);
    unsigned r = (u + 0x7fffu + ((u >> 16) & 1u)) >> 16;
    return (unsigned short)r;
}
__device__ __forceinline__ void split_bf16(float v, unsigned short& hi, unsigned short& lo) {
    hi = bf16_rne(v);
    float hf = __uint_as_float(((unsigned)hi) << 16);
    lo = bf16_rne(v - hf);
}

// async 16B/lane global->LDS DMA; lds base must be wave-uniform (dest = base + lane*16)
__device__ __forceinline__ void glds16(const unsigned short* g, unsigned short* l) {
    __builtin_amdgcn_global_load_lds(
        (const __attribute__((address_space(1))) unsigned*)g,
        (__attribute__((address_space(3))) unsigned*)l, 16, 0, 0);
}

// merged converts: bid<2048 -> W repack/split; bid>=2048 -> X transpose/split.
// W[o=g*256+c][i][j] -> Wa[r=c*4+g][k=j*256+i].  x[b][c][t] -> Xpad[b][t+1][c].
__global__ void convert_kernel(const float* __restrict__ W,
                               const float* __restrict__ x,
                               unsigned short* __restrict__ Whi,
                               unsigned short* __restrict__ Wlo,
                               unsigned short* __restrict__ Xhi,
                               unsigned short* __restrict__ Xlo) {
    __shared__ float tile[64][69];      // 69 mod 32 = 5 -> conflict-free both phases
    const int bid = blockIdx.x;
    const int tid = threadIdx.x;
    if (bid < 2048) {
        int e = bid * 256 + tid;        // 1024*512 elements
        int r = e >> 9, k = e & 511;
        int g = r & 3, c = r >> 2;
        int j = k >> 8, i = k & 255;
        float v = W[((size_t)((g << 8) + c)) * 512 + i * 2 + j];
        unsigned short hi, lo;
        split_bf16(v, hi, lo);
        Whi[e] = hi;
        Wlo[e] = lo;
        return;
    }
    const int b2 = bid - 2048;
    const int t0 = (b2 & 63) * 64;
    const int c0 = ((b2 >> 6) & 3) * 64;
    const int b  = b2 >> 8;

    {   // read: float4 along t, 16 rows per pass
        int j4 = (tid & 15) * 4, r16 = tid >> 4;
#pragma unroll
        for (int p = 0; p < 4; p++) {
            int i = p * 16 + r16;
            float4 v = *(const float4*)&x[((size_t)(b * 256 + c0 + i)) * T_ + t0 + j4];
            tile[i][j4] = v.x; tile[i][j4 + 1] = v.y;
            tile[i][j4 + 2] = v.z; tile[i][j4 + 3] = v.w;
        }
    }
    if (t0 == 0 && tid < 64) {   // zero pad row (x[-1] = 0)
        size_t z = (size_t)b * TP * 256 + c0 + tid;
        Xhi[z] = 0; Xlo[z] = 0;
    }
    __syncthreads();
    {   // write: 4 consecutive channels per thread, packed uint2 (8B) stores
        const int cslot = tid & 15, trow = tid >> 4;
#pragma unroll
        for (int p = 0; p < 4; p++) {
            int t = p * 16 + trow;
            unsigned hi0, hi1, lo0, lo1;
            {
                unsigned short h, l;
                split_bf16(tile[cslot * 4 + 0][t], h, l);
                hi0 = h; lo0 = l;
                split_bf16(tile[cslot * 4 + 1][t], h, l);
                hi0 |= ((unsigned)h) << 16; lo0 |= ((unsigned)l) << 16;
                split_bf16(tile[cslot * 4 + 2][t], h, l);
                hi1 = h; lo1 = l;
                split_bf16(tile[cslot * 4 + 3][t], h, l);
                hi1 |= ((unsigned)h) << 16; lo1 |= ((unsigned)l) << 16;
            }
            size_t idx = ((size_t)b * TP + t0 + t + 1) * 256 + c0 + cslot * 4;
            uint2 ph; ph.x = hi0; ph.y = hi1;
            uint2 pl; pl.x = lo0; pl.y = lo1;
            *(uint2*)&Xhi[idx] = ph;
            *(uint2*)&Xlo[idx] = pl;
        }
    }
}

// C[r=1024][n=32768] = Wa · Xb^T, split-bf16 MFMA (3 products).
// Round 8 = round 7 (128x128, BK=32, 2 blocks/CU, XOR swizzle, 3-phase
// counted vmcnt) restructured to 4 WAVES x 64x64 TILES (256 threads).
// Rationale (pipe accounting, m134/m119 constants): per SIMD, MFMA demand
// ~119K cyc (matches measured MfmaUtil 43%); LDS-read pipe demand was
// 8blk x 8w x 16ks x 12 ds_read x 12cy = 147K cyc/CU (+32K write) = 68% of
// wall -> LDS data pipe is the bottleneck. Square 64x64 wave tiles cut the
// read:MFMA ratio 0.5 -> 0.33 (A-frags reused over 4 n-subtiles, B over 4
// m-subtiles): read demand 147K -> 98K cyc. Same LDS footprint, cheaper
// 4-wave barriers. Staging: 2 DMAs/plane/wave; FIFO ledger re-derived:
// prologue vmcnt(4); loop P0 vmcnt(6), P1 vmcnt(6), P2 vmcnt(4).
// LDS planes (ushort idx): AH+0, AL+4096, BH+8192, BL+12288; dbuf +16384.
__launch_bounds__(256, 2)
__global__ void gemm_mfma_kernel(const unsigned short* __restrict__ Xhi,
                                 const unsigned short* __restrict__ Xlo,
                                 const unsigned short* __restrict__ Whi,
                                 const unsigned short* __restrict__ Wlo,
                                 const float* __restrict__ bias,
                                 __half* __restrict__ fw,
                                 __half* __restrict__ izw,
                                 __half* __restrict__ ow,
                                 float* __restrict__ Aw,
                                 float* __restrict__ Bw)
{
    __shared__ unsigned short smem_us[32768];   // 64 KiB

    const int tid  = threadIdx.x;
    const int wave = tid >> 6, lane = tid & 63;   // wave 0..3
    const int q = lane >> 4, mr = lane & 15;
    const int wm = wave >> 1, wn = wave & 1;      // 2 x 2 wave grid (M x N)

    // grid: 2048 = 8 xcd x (32 n-tiles x 8 r, r fastest -> X-tile L2-resident)
    const int bid   = blockIdx.x;
    const int xcd   = bid & 7;
    const int idx   = bid >> 3;                  // 0..255
    const int n_blk = xcd * 32 + (idx >> 3);     // 0..255
    const int r_blk = idx & 7;                   // 0..7
    const int r0 = r_blk * 128;
    const int n0 = n_blk * 128;
    const int bb = n0 >> 12;
    const int t0 = n0 & (T_ - 1);

    // staging: wave w stages rows w*32..w*32+31 of each plane; 2 DMAs per plane.
    // XOR-swizzled source slice (within the row's contiguous 64B window).
    const int lrow = lane >> 2;                              // 0..15
    const int lcol = (((lane & 3) ^ ((lrow >> 1) & 3)) * 8); // swizzled ushort offset
    const size_t wAoff = (size_t)(r0 + wave * 32 + lrow) * 512 + lcol;
    const unsigned short* pWh0 = Whi + wAoff;
    const unsigned short* pWh1 = pWh0 + 16 * 512;
    const unsigned short* pWl0 = Wlo + wAoff;
    const unsigned short* pWl1 = pWl0 + 16 * 512;
    const size_t xBoff = ((size_t)bb * TP + t0 + wave * 32 + lrow) * 256 + lcol;
    const unsigned short* pXh0 = Xhi + xBoff;
    const unsigned short* pXh1 = pXh0 + 16 * 256;
    const unsigned short* pXl0 = Xlo + xBoff;
    const unsigned short* pXl1 = pXl0 + 16 * 256;

    // fragment read bases (ushort offsets within one plane, swizzled slice)
    const int swz = (q ^ ((mr >> 1) & 3)) * 8;
    const int aoffb = (wm * 64 + mr) * 32 + swz;   // + v*512, v=0..3
    const int boffb = (wn * 64 + mr) * 32 + swz;   // + u*512, u=0..3
    const int wst = wave * 1024;                   // wave staging offset in plane

    floatx4 acc[4][4];
#pragma unroll
    for (int v = 0; v < 4; v++)
#pragma unroll
        for (int u = 0; u < 4; u++) acc[v][u] = (floatx4){0.f, 0.f, 0.f, 0.f};

    // prologue: stage K-step 0 into buffer 0, order AH,BH,BL,AL (oldest first)
    glds16(pWh0, smem_us + wst);                glds16(pWh1, smem_us + wst + 512);
    glds16(pXh0, smem_us + 8192 + wst);         glds16(pXh1, smem_us + 8192 + wst + 512);
    glds16(pXl0, smem_us + 12288 + wst);        glds16(pXl1, smem_us + 12288 + wst + 512);
    glds16(pWl0, smem_us + 4096 + wst);         glds16(pWl1, smem_us + 4096 + wst + 512);
    asm volatile("s_waitcnt vmcnt(4)" ::: "memory");   // AH,BH landed; BL,AL in flight
    __builtin_amdgcn_s_barrier();
    __builtin_amdgcn_sched_barrier(0);

#pragma unroll 2
    for (int i = 0; i < 16; ++i) {
        const int cur = i & 1, nxt = cur ^ 1;
        const unsigned kk = (unsigned)(((i + 1) & 15) * 32);   // wrap keeps counts uniform
        const unsigned short* AHc = smem_us + cur * 16384;
        const unsigned short* ALc = AHc + 4096;
        const unsigned short* BHc = AHc + 8192;
        const unsigned short* BLc = AHc + 12288;
        unsigned short* dAH = smem_us + nxt * 16384 + wst;
        unsigned short* dAL = dAH + 4096;
        unsigned short* dBH = dAH + 8192;
        unsigned short* dBL = dAH + 12288;

        short8 ah[4], bh[4];

        // ---------- P0: hi*hi ----------
#pragma unroll
        for (int v = 0; v < 4; ++v) ah[v] = *(const short8*)(AHc + aoffb + v * 512);
#pragma unroll
        for (int u = 0; u < 4; ++u) bh[u] = *(const short8*)(BHc + boffb + u * 512);
        glds16(pWh0 + kk, dAH); glds16(pWh1 + kk, dAH + 512);
        glds16(pXh0 + kk, dBH); glds16(pXh1 + kk, dBH + 512);
        asm volatile("s_waitcnt lgkmcnt(0)" ::: "memory");
        __builtin_amdgcn_sched_barrier(0);
        __builtin_amdgcn_s_setprio(1);
#pragma unroll
        for (int v = 0; v < 4; ++v)
#pragma unroll
            for (int u = 0; u < 4; ++u)
                acc[v][u] = __builtin_amdgcn_mfma_f32_16x16x32_bf16(ah[v], bh[u], acc[v][u], 0, 0, 0);
        __builtin_amdgcn_s_setprio(0);
        asm volatile("s_waitcnt vmcnt(6)" ::: "memory");   // BL[cur] landed
        __builtin_amdgcn_s_barrier();
        __builtin_amdgcn_sched_barrier(0);

        // ---------- P1: hi*lo ----------
        {
            short8 bl[4];
#pragma unroll
            for (int u = 0; u < 4; ++u) bl[u] = *(const short8*)(BLc + boffb + u * 512);
            glds16(pXl0 + kk, dBL); glds16(pXl1 + kk, dBL + 512);
            asm volatile("s_waitcnt lgkmcnt(0)" ::: "memory");
            __builtin_amdgcn_sched_barrier(0);
            __builtin_amdgcn_s_setprio(1);
#pragma unroll
            for (int v = 0; v < 4; ++v)
#pragma unroll
                for (int u = 0; u < 4; ++u)
                    acc[v][u] = __builtin_amdgcn_mfma_f32_16x16x32_bf16(ah[v], bl[u], acc[v][u], 0, 0, 0);
            __builtin_amdgcn_s_setprio(0);
        }
        asm volatile("s_waitcnt vmcnt(6)" ::: "memory");   // AL[cur] landed
        __builtin_amdgcn_s_barrier();
        __builtin_amdgcn_sched_barrier(0);

        // ---------- P2: lo*hi ----------
        {
            short8 al[4];
#pragma unroll
            for (int v = 0; v < 4; ++v) al[v] = *(const short8*)(ALc + aoffb + v * 512);
            glds16(pWl0 + kk, dAL); glds16(pWl1 + kk, dAL + 512);
            asm volatile("s_waitcnt lgkmcnt(0)" ::: "memory");
            __builtin_amdgcn_sched_barrier(0);
            __builtin_amdgcn_s_setprio(1);
#pragma unroll
            for (int v = 0; v < 4; ++v)
#pragma unroll
                for (int u = 0; u < 4; ++u)
                    acc[v][u] = __builtin_amdgcn_mfma_f32_16x16x32_bf16(al[v], bh[u], acc[v][u], 0, 0, 0);
            __builtin_amdgcn_s_setprio(0);
        }
        asm volatile("s_waitcnt vmcnt(4)" ::: "memory");   // AH,BH[nxt] landed
        __builtin_amdgcn_s_barrier();
        __builtin_amdgcn_sched_barrier(0);
    }

    // ---------- epilogue ----------
    asm volatile("s_waitcnt vmcnt(0)" ::: "memory");   // drain wrap-staging junk DMAs
    __syncthreads();                     // LDS reused below
    __half* epf = (__half*)smem_us;      // [128][36] f16, 72B rows (conflict-free t-phase)
    __half* epz = epf + 128 * 36;
    __half* epo = epz + 128 * 36;        // total 27,648 B < 64 KiB
    const int ch_base = r0 >> 2;         // 32 channels per block

#pragma unroll
    for (int v = 0; v < 4; ++v) {
        const int cl = wm * 16 + v * 4 + q;          // local channel 0..31
        const int ch = ch_base + cl;
        const float bz  = bias[ch];
        const float bf_ = bias[256 + ch];
        const float bo  = bias[512 + ch];
        const float bi  = bias[768 + ch];
#pragma unroll
        for (int u = 0; u < 4; ++u) {
            const int t_l = wn * 64 + u * 16 + mr;   // local t 0..127
            float zv = ftanh(acc[v][u][0] + bz);
            float fv = fsig(acc[v][u][1] + bf_);
            float ov = fsig(acc[v][u][2] + bo);
            float iv = fsig(acc[v][u][3] + bi);
            const int off = t_l * 36 + cl;
            epf[off] = __float2half(fv);             // same f16 rounding as before
            epz[off] = __float2half(iv * zv);
            epo[off] = __float2half(ov);
        }
    }
    __syncthreads();

    // coalesced f16 stores: 2 threads per t-row, 16 channels (32B) each
    {
        const int t_r = tid >> 1;                    // 0..127
        const int c16 = (tid & 1) << 4;              // 0 or 16
        const size_t gbase = ((size_t)bb * T_ + t0 + t_r) * 256 + ch_base + c16;
        const int lb = t_r * 36 + c16;               // 8B-aligned
        union { uint2 u2[4]; uint4 u4[2]; } pk;
#pragma unroll
        for (int j = 0; j < 4; ++j) pk.u2[j] = *(const uint2*)&epf[lb + j * 4];
        *(uint4*)&fw[gbase] = pk.u4[0];
        *(uint4*)&fw[gbase + 8] = pk.u4[1];
#pragma unroll
        for (int j = 0; j < 4; ++j) pk.u2[j] = *(const uint2*)&epz[lb + j * 4];
        *(uint4*)&izw[gbase] = pk.u4[0];
        *(uint4*)&izw[gbase + 8] = pk.u4[1];
#pragma unroll
        for (int j = 0; j < 4; ++j) pk.u2[j] = *(const uint2*)&epo[lb + j * 4];
        *(uint4*)&ow[gbase] = pk.u4[0];
        *(uint4*)&ow[gbase + 8] = pk.u4[1];
    }

    // fused scan phase 1: per-chunk (A = prod f, B = affine end); 4 chunks x 32 ch
    if (tid < 128) {
        const int chunk = tid >> 5;                  // 0..3
        const int c = tid & 31;
        float A = 1.0f, Bv = 0.0f;
        const int base = (chunk * 32) * 36 + c;
#pragma unroll 4
        for (int j = 0; j < 32; ++j) {
            float f  = __half2float(epf[base + j * 36]);
            float iz = __half2float(epz[base + j * 36]);
            Bv = fmaf(f, Bv, iz);
            A *= f;
        }
        const int chunk_abs = (t0 >> 5) + chunk;
        const size_t aidx = ((size_t)bb * NCH + chunk_abs) * 256 + ch_base + c;
        Aw[aidx] = A;
        Bw[aidx] = Bv;
    }
}

// Phase 3 (merged with old phase 2): each block computes its own carry from
// the chunk summaries (predicated 16-wide batched loads; Aw/Bw are L2-hot
// 256KB), then replays the recurrence and writes out[b][c][t] transposed.
__global__ void scan_phase3(const __half* __restrict__ fw, const __half* __restrict__ izw,
                            const __half* __restrict__ ow,
                            const float* __restrict__ Aw, const float* __restrict__ Bw,
                            float* __restrict__ out)
{
    __shared__ float hbuf[CL][257];
    __shared__ float carry_s[256];
    int b = blockIdx.y, ch = blockIdx.x;
    int tid = threadIdx.x;

    {   // carry over chunks 0..ch-1 for channel tid (exclusive scan, batched)
        const int c = tid;
        float carry = 0.0f;
        for (int g = 0; g < 8; ++g) {
            if (g * 16 >= ch) break;
            float Ar[16], Br[16];
#pragma unroll
            for (int j = 0; j < 16; ++j) {
                int jj = g * 16 + j;
                bool ok = jj < ch;
                size_t idx2 = ((size_t)(b * NCH + (ok ? jj : 0))) * CO + c;
                Ar[j] = ok ? Aw[idx2] : 1.0f;
                Br[j] = ok ? Bw[idx2] : 0.0f;
            }
#pragma unroll
            for (int j = 0; j < 16; ++j) carry = fmaf(Ar[j], carry, Br[j]);
        }
        carry_s[c] = carry;
    }
    __syncthreads();

    if (tid < 128) {
        const int c2 = tid * 2;
        float cs0 = carry_s[c2];
        float cs1 = carry_s[c2 + 1];
        size_t base = ((size_t)(b * T_ + ch * CL)) * CO + c2;
#pragma unroll 4
        for (int tt = 0; tt < CL; tt++) {
            __half2 f2  = *(const __half2*)&fw [base + (size_t)tt * CO];
            __half2 iz2 = *(const __half2*)&izw[base + (size_t)tt * CO];
            __half2 o2  = *(const __half2*)&ow [base + (size_t)tt * CO];
            float2 f  = __half22float2(f2);
            float2 iz = __half22float2(iz2);
            float2 o  = __half22float2(o2);
            cs0 = fmaf(f.x, cs0, iz.x);
            cs1 = fmaf(f.y, cs1, iz.y);
            hbuf[tt][c2]     = o.x * cs0;
            hbuf[tt][c2 + 1] = o.y * cs1;
        }
    }
    __syncthreads();
    int tt = threadIdx.x & 31;
    int cr = threadIdx.x >> 5;
#pragma unroll
    for (int w = 0; w < 32; w++) {
        int cc = cr + w * 8;
        out[((size_t)(b * CO + cc)) * T_ + ch * CL + tt] = hbuf[tt][cc];
    }
}

extern "C" void kernel_launch(void* const* d_in, const int* in_sizes, int n_in,
                              void* d_out, int out_size, void* d_ws, size_t ws_size,
                              hipStream_t stream) {
    const float* x    = (const float*)d_in[0];
    const float* W    = (const float*)d_in[1];
    const float* bias = (const float*)d_in[2];
    float* out = (float*)d_out;
    float* ws  = (float*)d_ws;

    unsigned short* Xhi = (unsigned short*)(ws + OFF_XHI);
    unsigned short* Xlo = (unsigned short*)(ws + OFF_XLO);
    unsigned short* Whi = (unsigned short*)(ws + OFF_WHI);
    unsigned short* Wlo = (unsigned short*)(ws + OFF_WLO);
    __half* fw  = (__half*)(ws + OFF_F16);
    __half* izw = (__half*)(ws + OFF_IZ16);
    __half* ow  = (__half*)(ws + OFF_O16);
    float* Aw  = ws + OFF_A;
    float* Bw  = ws + OFF_B;

    convert_kernel<<<4096, 256, 0, stream>>>(W, x, Whi, Wlo, Xhi, Xlo);
    gemm_mfma_kernel<<<(NN / 128) * (O4 / 128), 256, 0, stream>>>(
        Xhi, Xlo, Whi, Wlo, bias, fw, izw, ow, Aw, Bw);
    scan_phase3<<<dim3(NCH, B_), CO, 0, stream>>>(fw, izw, ow, Aw, Bw, out);
}